// Round 2
// baseline (1354.457 us; speedup 1.0000x reference)
//
#include <hip/hip_runtime.h>
#include <math.h>

#define N_TOK 65536
#define H_DIM 1024

typedef __attribute__((ext_vector_type(8))) short bf16x8;
typedef __attribute__((ext_vector_type(16))) float f32x16;

// ---------------- ws layout (bytes); total need ~277 MB ----------------
static const size_t WS_CNT   = 0;                       // int[4]
static const size_t WS_OFFS  = 64;                      // int[4]
static const size_t WS_PERM  = 128;                     // int[3*N_TOK]
static const size_t WS_WT1   = 1ull << 20;              // bf16 [3][1024][1024]
static const size_t WS_WT3   = WS_WT1 + 6291456ull;
static const size_t WS_WT2   = WS_WT3 + 6291456ull;
static const size_t WS_XB    = 20ull << 20;             // bf16 [N][H] = 128MB
static const size_t WS_INNER = WS_XB + 134217728ull;    // bf16 [N][H] = 128MB

static __device__ __forceinline__ unsigned short f2bf(float f) {
  union { float f; unsigned int u; } v; v.f = f;
  unsigned int r = v.u + 0x7fffu + ((v.u >> 16) & 1u);
  return (unsigned short)(r >> 16);
}

// async global->LDS DMA, 16B per lane; LDS dest = wave-uniform base + lane*16
static __device__ __forceinline__ void lds_dma16(const void* g, void* l) {
  __builtin_amdgcn_global_load_lds(
      (const __attribute__((address_space(1))) unsigned int*)g,
      (__attribute__((address_space(3))) unsigned int*)l, 16, 0, 0);
}

__global__ void init_kernel(int* cnt) {
  if (threadIdx.x < 4) cnt[threadIdx.x] = 0;
}

// one wave per row: 3 gate logits + gumbel argmax + x->bf16 conversion.
__global__ __launch_bounds__(1024) void gate_kernel(
    const float* __restrict__ x, const float* __restrict__ Wg,
    const float* __restrict__ bg, const float* __restrict__ gu,
    unsigned short* __restrict__ xb, int* __restrict__ cnt,
    int* __restrict__ perm)
{
  __shared__ float wg[3072];
  __shared__ int bexp[16];
  for (int i = threadIdx.x; i < 3072; i += 1024) wg[i] = Wg[i];
  __syncthreads();
  const int wave = threadIdx.x >> 6;
  const int lane = threadIdx.x & 63;
  const int n0 = blockIdx.x * 16;
  const int n = n0 + wave;
  const float4* xrow = (const float4*)(x + (size_t)n * H_DIM);
  unsigned short* xbrow = xb + (size_t)n * H_DIM;
  float s0 = 0.f, s1 = 0.f, s2 = 0.f;
#pragma unroll
  for (int j = 0; j < 4; j++) {
    float4 v = xrow[j * 64 + lane];
    int d0 = (j * 64 + lane) * 4;
    const float* w = &wg[d0 * 3];
    s0 += v.x * w[0] + v.y * w[3] + v.z * w[6] + v.w * w[9];
    s1 += v.x * w[1] + v.y * w[4] + v.z * w[7] + v.w * w[10];
    s2 += v.x * w[2] + v.y * w[5] + v.z * w[8] + v.w * w[11];
    uint2 p;
    p.x = (unsigned)f2bf(v.x) | ((unsigned)f2bf(v.y) << 16);
    p.y = (unsigned)f2bf(v.z) | ((unsigned)f2bf(v.w) << 16);
    ((uint2*)xbrow)[j * 64 + lane] = p;
  }
#pragma unroll
  for (int o = 32; o; o >>= 1) {
    s0 += __shfl_xor(s0, o);
    s1 += __shfl_xor(s1, o);
    s2 += __shfl_xor(s2, o);
  }
  if (lane == 0) {
    const float* u = gu + (size_t)n * 3;
    float l[3] = { s0 + bg[0], s1 + bg[1], s2 + bg[2] };
    int best = 0; float bs = -1e30f;
#pragma unroll
    for (int e = 0; e < 3; e++) {
      float uc = fminf(fmaxf(u[e], 1e-6f), 1.f - 1e-6f);
      float g = -logf(-logf(uc));
      float s = l[e] + g;
      if (s > bs) { bs = s; best = e; }   // strict > == first-max (jnp.argmax)
    }
    bexp[wave] = best;
  }
  __syncthreads();
  if (threadIdx.x == 0) {
    int lc[3] = {0, 0, 0};
    int lpos[16];
    for (int w = 0; w < 16; w++) lpos[w] = lc[bexp[w]]++;
    int lbase[3];
    for (int e = 0; e < 3; e++)
      lbase[e] = lc[e] ? atomicAdd(&cnt[e], lc[e]) : 0;
    for (int w = 0; w < 16; w++) {
      int e = bexp[w];
      perm[e * N_TOK + lbase[e] + lpos[w]] = n0 + w;
    }
  }
}

__global__ void offs_kernel(const int* __restrict__ cnt, int* __restrict__ offs) {
  offs[0] = 0; offs[1] = cnt[0]; offs[2] = cnt[0] + cnt[1]; offs[3] = N_TOK;
}

// W[e][d][h] fp32 -> Wt[e][h][d] bf16 (k-contiguous rows for MFMA B frags)
__global__ __launch_bounds__(256) void wcvt_kernel(
    const float* __restrict__ W1, const float* __restrict__ W3,
    const float* __restrict__ W2,
    unsigned short* __restrict__ wt1, unsigned short* __restrict__ wt3,
    unsigned short* __restrict__ wt2)
{
  const int z = blockIdx.z, e = z / 3, m = z % 3;
  const float* src = (m == 0 ? W1 : (m == 1 ? W3 : W2)) + ((size_t)e << 20);
  unsigned short* dst = (m == 0 ? wt1 : (m == 1 ? wt3 : wt2)) + ((size_t)e << 20);
  __shared__ float t[32][33];
  const int h0 = blockIdx.x * 32, d0 = blockIdx.y * 32;
  const int tx = threadIdx.x, ty = threadIdx.y;
#pragma unroll
  for (int i = 0; i < 4; i++)
    t[ty + i * 8][tx] = src[(size_t)(d0 + ty + i * 8) * H_DIM + h0 + tx];
  __syncthreads();
#pragma unroll
  for (int i = 0; i < 4; i++)
    dst[(size_t)(h0 + ty + i * 8) * H_DIM + d0 + tx] = f2bf(t[tx][ty + i * 8]);
}

// Fused h1/h3 GEMM + bias + activation -> inner (bf16, bucket-compacted).
// 128x128 tile, BK=64, lds-dma staging, 32x32x16 MFMA, LDS-packed epilogue.
__global__ __launch_bounds__(256, 2) void mlp1_kernel(
    const unsigned short* __restrict__ xb,
    const unsigned short* __restrict__ wt1,
    const unsigned short* __restrict__ wt3,
    const float* __restrict__ b1, const float* __restrict__ b3,
    const int* __restrict__ cnt, const int* __restrict__ offs,
    const int* __restrict__ perm,
    unsigned short* __restrict__ inner)
{
  const int e = blockIdx.z;
  const int ce = cnt[e];
  const int m0 = blockIdx.x * 128;
  if (m0 >= ce) return;
  const int n0 = blockIdx.y * 128;
  const int oe = offs[e];

  __shared__ short lds[3 * 8192];   // 48KB: A | B1 | B3, each [128][64]
  short* a_sh = lds;
  short* p_sh = lds + 8192;
  short* q_sh = lds + 16384;

  const int t = threadIdx.x;
  const int wave = t >> 6, lane = t & 63;
  const int lrow = lane >> 3;        // 0..7  (DMA row within 8-row group)
  const int lk   = (lane & 7) * 8;   // DMA k offset (shorts)

  const unsigned short* w1p = wt1 + ((size_t)e << 20);
  const unsigned short* w3p = wt3 + ((size_t)e << 20);

  const unsigned short* ga[4]; const unsigned short* gb1[4]; const unsigned short* gb3[4];
  short* la[4]; short* lp[4]; short* lq[4];
#pragma unroll
  for (int s = 0; s < 4; s++) {
    int row = wave * 32 + s * 8 + lrow;
    int g = perm[e * N_TOK + min(m0 + row, ce - 1)];
    ga[s]  = xb  + (size_t)g * H_DIM + lk;
    gb1[s] = w1p + (size_t)(n0 + row) * H_DIM + lk;
    gb3[s] = w3p + (size_t)(n0 + row) * H_DIM + lk;
    int ro = (wave * 32 + s * 8) * 64;
    la[s] = a_sh + ro; lp[s] = p_sh + ro; lq[s] = q_sh + ro;
  }

  const int wm = (wave & 1) * 64, wn = (wave >> 1) * 64;
  const int l31 = lane & 31, kh = lane >> 5;

  f32x16 acc1[2][2], acc3[2][2];
#pragma unroll
  for (int a = 0; a < 2; a++)
#pragma unroll
    for (int b = 0; b < 2; b++) {
      acc1[a][b] = (f32x16)(0.f);
      acc3[a][b] = (f32x16)(0.f);
    }

  for (int k0 = 0; k0 < H_DIM; k0 += 64) {
    __syncthreads();
#pragma unroll
    for (int s = 0; s < 4; s++) {
      lds_dma16(ga[s] + k0, la[s]);
      lds_dma16(gb1[s] + k0, lp[s]);
      lds_dma16(gb3[s] + k0, lq[s]);
    }
    __syncthreads();
#pragma unroll
    for (int ks = 0; ks < 64; ks += 16) {
      bf16x8 af[2], b1f[2], b3f[2];
#pragma unroll
      for (int i = 0; i < 2; i++)
        af[i] = *(const bf16x8*)&a_sh[(wm + i * 32 + l31) * 64 + ks + kh * 8];
#pragma unroll
      for (int j = 0; j < 2; j++) {
        b1f[j] = *(const bf16x8*)&p_sh[(wn + j * 32 + l31) * 64 + ks + kh * 8];
        b3f[j] = *(const bf16x8*)&q_sh[(wn + j * 32 + l31) * 64 + ks + kh * 8];
      }
#pragma unroll
      for (int i = 0; i < 2; i++)
#pragma unroll
        for (int j = 0; j < 2; j++) {
          acc1[i][j] = __builtin_amdgcn_mfma_f32_32x32x16_bf16(af[i], b1f[j], acc1[i][j], 0, 0, 0);
          acc3[i][j] = __builtin_amdgcn_mfma_f32_32x32x16_bf16(af[i], b3f[j], acc3[i][j], 0, 0, 0);
        }
    }
  }

  // epilogue: activation -> LDS pack (bf16 [128][128]) -> coalesced 256B rows
  __syncthreads();
  unsigned short* C = (unsigned short*)lds;
#pragma unroll
  for (int j = 0; j < 2; j++) {
    int col = n0 + wn + j * 32 + l31;
    float bb1 = b1[e * H_DIM + col];
    float bb3 = b3[e * H_DIM + col];
#pragma unroll
    for (int i = 0; i < 2; i++) {
#pragma unroll
      for (int reg = 0; reg < 16; reg++) {
        int row = wm + i * 32 + (reg & 3) + 8 * (reg >> 2) + 4 * kh;
        float h1 = acc1[i][j][reg] + bb1;
        float h3 = acc3[i][j][reg] + bb3;
        float a;
        if (e == 0)      a = h1 / (1.f + expf(-h1));                        // silu
        else if (e == 1) a = 0.5f * h1 * (1.f + erff(h1 * 0.70710678118f)); // exact gelu
        else             a = fmaxf(h1, 0.f);                                // relu
        C[row * 128 + wn + j * 32 + l31] = f2bf(a * h3);
      }
    }
  }
  __syncthreads();
#pragma unroll
  for (int sweep = 0; sweep < 8; sweep++) {
    int row = sweep * 16 + (t >> 4);
    int rr = m0 + row;
    if (rr < ce) {
      uint4 v = *(const uint4*)&C[row * 128 + (t & 15) * 8];
      *(uint4*)&inner[(size_t)(oe + rr) * H_DIM + n0 + (t & 15) * 8] = v;
    }
  }
}

// out = inner @ W2t + b2, scattered back to original row order (fp32)
__global__ __launch_bounds__(256, 2) void mlp2_kernel(
    const unsigned short* __restrict__ inner,
    const unsigned short* __restrict__ wt2,
    const float* __restrict__ b2,
    const int* __restrict__ cnt, const int* __restrict__ offs,
    const int* __restrict__ perm,
    float* __restrict__ out)
{
  const int e = blockIdx.z;
  const int ce = cnt[e];
  const int m0 = blockIdx.x * 128;
  if (m0 >= ce) return;
  const int n0 = blockIdx.y * 128;
  const int oe = offs[e];

  __shared__ short lds[2 * 8192];   // 32KB: A | B, each [128][64]
  short* a_sh = lds;
  short* p_sh = lds + 8192;

  const int t = threadIdx.x;
  const int wave = t >> 6, lane = t & 63;
  const int lrow = lane >> 3;
  const int lk   = (lane & 7) * 8;
  const unsigned short* w2p = wt2 + ((size_t)e << 20);

  const unsigned short* ga[4]; const unsigned short* gb[4];
  short* la[4]; short* lp[4];
#pragma unroll
  for (int s = 0; s < 4; s++) {
    int row = wave * 32 + s * 8 + lrow;
    int r = min(m0 + row, ce - 1);
    ga[s] = inner + (size_t)(oe + r) * H_DIM + lk;
    gb[s] = w2p + (size_t)(n0 + row) * H_DIM + lk;
    int ro = (wave * 32 + s * 8) * 64;
    la[s] = a_sh + ro; lp[s] = p_sh + ro;
  }

  const int wm = (wave & 1) * 64, wn = (wave >> 1) * 64;
  const int l31 = lane & 31, kh = lane >> 5;

  f32x16 acc[2][2];
#pragma unroll
  for (int a = 0; a < 2; a++)
#pragma unroll
    for (int b = 0; b < 2; b++) acc[a][b] = (f32x16)(0.f);

  for (int k0 = 0; k0 < H_DIM; k0 += 64) {
    __syncthreads();
#pragma unroll
    for (int s = 0; s < 4; s++) {
      lds_dma16(ga[s] + k0, la[s]);
      lds_dma16(gb[s] + k0, lp[s]);
    }
    __syncthreads();
#pragma unroll
    for (int ks = 0; ks < 64; ks += 16) {
      bf16x8 af[2], bf[2];
#pragma unroll
      for (int i = 0; i < 2; i++)
        af[i] = *(const bf16x8*)&a_sh[(wm + i * 32 + l31) * 64 + ks + kh * 8];
#pragma unroll
      for (int j = 0; j < 2; j++)
        bf[j] = *(const bf16x8*)&p_sh[(wn + j * 32 + l31) * 64 + ks + kh * 8];
#pragma unroll
      for (int i = 0; i < 2; i++)
#pragma unroll
        for (int j = 0; j < 2; j++)
          acc[i][j] = __builtin_amdgcn_mfma_f32_32x32x16_bf16(af[i], bf[j], acc[i][j], 0, 0, 0);
    }
  }

  // epilogue: two-pass LDS pack (fp32 [64][128] = 32KB), 512B coalesced rows,
  // scatter rows via perm
  float* C = (float*)lds;
#pragma unroll
  for (int half = 0; half < 2; half++) {
    __syncthreads();
    if ((wave & 1) == half) {
#pragma unroll
      for (int j = 0; j < 2; j++) {
        float bb2 = b2[e * H_DIM + n0 + wn + j * 32 + l31];
#pragma unroll
        for (int i = 0; i < 2; i++) {
#pragma unroll
          for (int reg = 0; reg < 16; reg++) {
            int row = i * 32 + (reg & 3) + 8 * (reg >> 2) + 4 * kh;
            C[row * 128 + wn + j * 32 + l31] = acc[i][j][reg] + bb2;
          }
        }
      }
    }
    __syncthreads();
#pragma unroll
    for (int sweep = 0; sweep < 8; sweep++) {
      int row = sweep * 8 + (t >> 5);
      int rr = m0 + half * 64 + row;
      if (rr < ce) {
        int g = perm[e * N_TOK + rr];
        uint4 v = *(const uint4*)&C[row * 128 + (t & 31) * 4];
        *(uint4*)&out[(size_t)g * H_DIM + n0 + (t & 31) * 4] = v;
      }
    }
  }
}

extern "C" void kernel_launch(void* const* d_in, const int* in_sizes, int n_in,
                              void* d_out, int out_size, void* d_ws, size_t ws_size,
                              hipStream_t stream)
{
  const float* x  = (const float*)d_in[0];
  const float* W1 = (const float*)d_in[1];
  const float* b1 = (const float*)d_in[2];
  const float* W2 = (const float*)d_in[3];
  const float* b2 = (const float*)d_in[4];
  const float* W3 = (const float*)d_in[5];
  const float* b3 = (const float*)d_in[6];
  const float* Wg = (const float*)d_in[7];
  const float* bg = (const float*)d_in[8];
  const float* gu = (const float*)d_in[9];
  float* out = (float*)d_out;

  char* ws = (char*)d_ws;
  int* cnt  = (int*)(ws + WS_CNT);
  int* offs = (int*)(ws + WS_OFFS);
  int* perm = (int*)(ws + WS_PERM);
  unsigned short* wt1 = (unsigned short*)(ws + WS_WT1);
  unsigned short* wt3 = (unsigned short*)(ws + WS_WT3);
  unsigned short* wt2 = (unsigned short*)(ws + WS_WT2);
  unsigned short* xb  = (unsigned short*)(ws + WS_XB);
  unsigned short* inner = (unsigned short*)(ws + WS_INNER);

  init_kernel<<<1, 64, 0, stream>>>(cnt);
  gate_kernel<<<N_TOK / 16, 1024, 0, stream>>>(x, Wg, bg, gu, xb, cnt, perm);
  offs_kernel<<<1, 1, 0, stream>>>(cnt, offs);
  wcvt_kernel<<<dim3(32, 32, 9), dim3(32, 8), 0, stream>>>(W1, W3, W2, wt1, wt3, wt2);
  mlp1_kernel<<<dim3(512, 8, 3), 256, 0, stream>>>(xb, wt1, wt3, b1, b3, cnt, offs, perm, inner);
  mlp2_kernel<<<dim3(512, 8, 3), 256, 0, stream>>>(inner, wt2, b2, cnt, offs, perm, out);
}